// Round 6
// baseline (333.055 us; speedup 1.0000x reference)
//
#include <hip/hip_runtime.h>

#define D 64
#define CHUNK 4096      // edges per partition block
#define BSHIFT 8        // bucket = dst >> 8 (256 nodes per bucket)

typedef unsigned int uint;
typedef unsigned short ushort;

// fp32 -> bf16 round-to-nearest-even (inputs are post-relu finite)
__device__ __forceinline__ uint f2bf(float f) {
    uint u = __float_as_uint(f);
    return (u + 0x7fffu + ((u >> 16) & 1u)) >> 16;
}
__device__ __forceinline__ uint pack2(float a, float b) {
    return f2bf(fmaxf(a, 0.f)) | (f2bf(fmaxf(b, 0.f)) << 16);
}

// decode a uint4 (8 packed bf16) and accumulate into even/odd fp32 accs
#define ACC8(v, aE, aO) do {                                                   \
    aE[0] += __uint_as_float((v).x << 16);                                     \
    aO[0] += __uint_as_float((v).x & 0xffff0000u);                             \
    aE[1] += __uint_as_float((v).y << 16);                                     \
    aO[1] += __uint_as_float((v).y & 0xffff0000u);                             \
    aE[2] += __uint_as_float((v).z << 16);                                     \
    aO[2] += __uint_as_float((v).z & 0xffff0000u);                             \
    aE[3] += __uint_as_float((v).w << 16);                                     \
    aO[3] += __uint_as_float((v).w & 0xffff0000u);                             \
} while (0)

// ---------------------------------------------------------------------------
// Node-per-lane 2-layer MLP: lane processes one whole node row.
// Weight/bias indices are wave-uniform -> scalar s_load broadcasts (no weight
// VGPRs, no cross-lane ops). 64 independent fmac chains = issue-bound.
// ---------------------------------------------------------------------------
template <bool BF16OUT>
__device__ __forceinline__ void mlp2_rowlane(
    const float* __restrict__ X,
    const float* __restrict__ W1r, const float* __restrict__ b1r,
    const float* __restrict__ W2r, const float* __restrict__ b2r,
    int node, int N, ushort* __restrict__ out16, float* __restrict__ out32)
{
    const bool act = node < N;
    const float* xr = X + (size_t)(act ? node : 0) * D;

    float h1[D];
    #pragma unroll
    for (int j = 0; j < D; ++j) h1[j] = b1r[j];

    #pragma unroll
    for (int k4 = 0; k4 < D; k4 += 4) {
        float4 xv = *(const float4*)(xr + k4);
        const float* w0 = W1r + k4 * D;
        #pragma unroll
        for (int j = 0; j < D; ++j) h1[j] = fmaf(xv.x, w0[j], h1[j]);
        #pragma unroll
        for (int j = 0; j < D; ++j) h1[j] = fmaf(xv.y, w0[D + j], h1[j]);
        #pragma unroll
        for (int j = 0; j < D; ++j) h1[j] = fmaf(xv.z, w0[2 * D + j], h1[j]);
        #pragma unroll
        for (int j = 0; j < D; ++j) h1[j] = fmaf(xv.w, w0[3 * D + j], h1[j]);
    }
    #pragma unroll
    for (int j = 0; j < D; ++j) h1[j] = fmaxf(h1[j], 0.f);

    float h2[D];
    #pragma unroll
    for (int j = 0; j < D; ++j) h2[j] = b2r[j];
    #pragma unroll
    for (int k = 0; k < D; ++k) {           // full unroll: h1[k] stays in regs
        const float hk = h1[k];
        const float* wr = W2r + k * D;
        #pragma unroll
        for (int j = 0; j < D; ++j) h2[j] = fmaf(hk, wr[j], h2[j]);
    }

    if (BF16OUT) {
        if (act) {
            uint4* dstp = (uint4*)(out16 + (size_t)node * D);
            #pragma unroll
            for (int q = 0; q < 8; ++q) {
                uint4 v;
                v.x = pack2(h2[8 * q + 0], h2[8 * q + 1]);
                v.y = pack2(h2[8 * q + 2], h2[8 * q + 3]);
                v.z = pack2(h2[8 * q + 4], h2[8 * q + 5]);
                v.w = pack2(h2[8 * q + 6], h2[8 * q + 7]);
                dstp[q] = v;
            }
        }
    } else {
        if (act) {
            float4* dstp = (float4*)(out32 + (size_t)node * D);
            #pragma unroll
            for (int q = 0; q < 16; ++q) {
                float4 v = { fmaxf(h2[4 * q + 0], 0.f), fmaxf(h2[4 * q + 1], 0.f),
                             fmaxf(h2[4 * q + 2], 0.f), fmaxf(h2[4 * q + 3], 0.f) };
                dstp[q] = v;
            }
        }
    }
}

// ---------------------------------------------------------------------------
// K1: blocks [0,NBA): per-chunk bucket histogram + global per-node histogram.
//     blocks [NBA, NBA+NMB): message MLP (node-per-lane), msg stored bf16.
// ---------------------------------------------------------------------------
__global__ __launch_bounds__(256) void k1_mlp_hist(
    const float* __restrict__ y,
    const float* __restrict__ W1, const float* __restrict__ b1,
    const float* __restrict__ W2, const float* __restrict__ b2,
    ushort* __restrict__ msg16, int N,
    const int* __restrict__ dst, int* __restrict__ counts,
    int* __restrict__ histG, int E, int NBA)
{
    __shared__ int lhist[256];
    if ((int)blockIdx.x < NBA) {
        const int t = threadIdx.x;
        lhist[t] = 0;
        __syncthreads();
        const int cbase = blockIdx.x * CHUNK;
        for (int j = t; j < CHUNK; j += 256) {
            int e = cbase + j;
            if (e < E) {
                int d = dst[e];
                atomicAdd(&lhist[d >> BSHIFT], 1);
                atomicAdd(&counts[d], 1);
            }
        }
        __syncthreads();
        histG[blockIdx.x * 256 + t] = lhist[t];
    } else {
        const int blk = blockIdx.x - NBA;
        if (blk == 0 && threadIdx.x < D) msg16[(size_t)N * D + threadIdx.x] = 0;
        const int node = blk * 256 + threadIdx.x;
        mlp2_rowlane<true>(y, W1, b1, W2, b2, node, N, msg16, nullptr);
    }
}

// ---------------------------------------------------------------------------
// K2: blocks [0,256): per-bucket scan over chunk histograms -> startG, tot.
//     blocks [256,256+NBpad): per-chunk sums of PADDED node counts -> bsumP.
// ---------------------------------------------------------------------------
__global__ __launch_bounds__(256) void k2_scans(
    const int* __restrict__ histG, int* __restrict__ startG,
    int* __restrict__ tot,
    const int* __restrict__ counts, int* __restrict__ bsumP,
    int N, int NBA)
{
    __shared__ int tmp[256];
    const int t = threadIdx.x;
    if (blockIdx.x < 256) {
        const int b = blockIdx.x;
        const int i0 = 2 * t, i1 = 2 * t + 1;
        int v0 = (i0 < NBA) ? histG[i0 * 256 + b] : 0;
        int v1 = (i1 < NBA) ? histG[i1 * 256 + b] : 0;
        int s = v0 + v1;
        int x = s; tmp[t] = x; __syncthreads();
        #pragma unroll
        for (int off = 1; off < 256; off <<= 1) {
            int add = (t >= off) ? tmp[t - off] : 0; __syncthreads();
            x += add; tmp[t] = x; __syncthreads();
        }
        int excl = x - s;
        if (i0 < NBA) startG[i0 * 256 + b] = excl;
        if (i1 < NBA) startG[i1 * 256 + b] = excl + v0;
        if (t == 255) tot[b] = x;
    } else {
        const int blk = blockIdx.x - 256;
        int i = blk * 256 + t;
        int c = (i < N) ? counts[i] : 0;
        int p = (c + 7) & ~7;   // padded to multiple of 8
        #pragma unroll
        for (int off = 32; off > 0; off >>= 1) p += __shfl_down(p, off, 64);
        if ((t & 63) == 0) tmp[t >> 6] = p;
        __syncthreads();
        if (t == 0) bsumP[blk] = tmp[0] + tmp[1] + tmp[2] + tmp[3];
    }
}

// ---------------------------------------------------------------------------
// K3: blocks [0,NBpad): padded exclusive scan -> offsets[] (+offsets[N]).
//     blocks [NBpad, NBpad+NBA): partition edges into bucket-grouped packedG.
// ---------------------------------------------------------------------------
__global__ __launch_bounds__(256) void k3_offsets_scatter(
    const int* __restrict__ counts, const int* __restrict__ bsumP,
    int* __restrict__ offsets, int N, int E, int NBpad,
    const int* __restrict__ src, const int* __restrict__ dst,
    const int* __restrict__ startG, const int* __restrict__ tot,
    uint* __restrict__ packedG)
{
    __shared__ int t1[256];
    __shared__ int t2[256];
    const int t = threadIdx.x;
    if ((int)blockIdx.x < NBpad) {
        int bx = (t < NBpad) ? bsumP[t] : 0;
        int x1 = bx; t1[t] = x1; __syncthreads();
        #pragma unroll
        for (int off = 1; off < 256; off <<= 1) {
            int add = (t >= off) ? t1[t - off] : 0; __syncthreads();
            x1 += add; t1[t] = x1; __syncthreads();
        }
        const int base = (blockIdx.x == 0) ? 0 : t1[blockIdx.x - 1];
        const int i = blockIdx.x * 256 + t;
        int c = (i < N) ? counts[i] : 0;
        int p = (c + 7) & ~7;
        int x2 = p; t2[t] = x2; __syncthreads();
        #pragma unroll
        for (int off = 1; off < 256; off <<= 1) {
            int add = (t >= off) ? t2[t - off] : 0; __syncthreads();
            x2 += add; t2[t] = x2; __syncthreads();
        }
        int excl = x2 - p + base;
        if (i < N) offsets[i] = excl;
        if (blockIdx.x == 0 && t == 0) offsets[N] = t1[NBpad - 1];
    } else {
        const int blk = blockIdx.x - NBpad;
        int tv = tot[t];
        int x = tv; t1[t] = x; __syncthreads();
        #pragma unroll
        for (int off = 1; off < 256; off <<= 1) {
            int add = (t >= off) ? t1[t - off] : 0; __syncthreads();
            x += add; t1[t] = x; __syncthreads();
        }
        t2[t] = (x - tv) + startG[blk * 256 + t];   // cursor per bucket
        __syncthreads();
        const int cbase = blk * CHUNK;
        for (int j = t; j < CHUNK; j += 256) {
            int e = cbase + j;
            if (e < E) {
                int s = src[e], d = dst[e];
                int pos = atomicAdd(&t2[d >> BSHIFT], 1);
                packedG[pos] = ((uint)(d & 255) << 16) | (uint)s;
            }
        }
    }
}

// ---------------------------------------------------------------------------
// K4: one block per bucket: place packed entries at final padded positions
// (single-writer region -> L2 merges 2B writes), fill padding with row N.
// ---------------------------------------------------------------------------
__global__ __launch_bounds__(256) void k4_place(
    const uint* __restrict__ packedG, const int* __restrict__ tot,
    const int* __restrict__ offsets,
    ushort* __restrict__ sortedG, int N)
{
    __shared__ int t1[256];
    __shared__ int sbase[256];
    __shared__ int cur[256];
    __shared__ int nxt[256];
    const int t = threadIdx.x;
    const int b = blockIdx.x;

    int tv = tot[t];
    int x = tv; t1[t] = x; __syncthreads();
    #pragma unroll
    for (int off = 1; off < 256; off <<= 1) {
        int add = (t >= off) ? t1[t - off] : 0; __syncthreads();
        x += add; t1[t] = x; __syncthreads();
    }
    sbase[t] = x - tv;
    const int node = b * 256 + t;
    cur[t] = (node < N) ? offsets[node] : 0;
    nxt[t] = (node < N) ? offsets[node + 1] : 0;
    __syncthreads();

    const int base_pk = sbase[b];
    const int cnt = tot[b];
    for (int i = t; i < cnt; i += 256) {
        uint e = packedG[base_pk + i];
        int dloc = e >> 16;
        int p = atomicAdd(&cur[dloc], 1);
        sortedG[p] = (ushort)(e & 0xffffu);
    }
    __syncthreads();
    if (node < N) {
        const ushort zr = (ushort)N;
        for (int p = cur[t]; p < nxt[t]; ++p) sortedG[p] = zr;  // <=7 pads
    }
}

// ---------------------------------------------------------------------------
// K5: gather segment-sum only (bf16 msg, padded CSR) -> z fp32.
// lane = (grp, sub): grp=lane>>3 picks the edge, sub=lane&7 picks 16B of the
// 128B row. All <=8 row loads of a batch are issued before any decode.
// ---------------------------------------------------------------------------
__global__ __launch_bounds__(256) void k5_gather(
    const ushort* __restrict__ msg16,
    const int* __restrict__ offsets, const ushort* __restrict__ sortedG,
    float* __restrict__ z, int n_nodes)
{
    const int lane = threadIdx.x & 63;
    const int sub = lane & 7;
    const int grp = lane >> 3;
    const int gw = blockIdx.x * 4 + (threadIdx.x >> 6);
    const int tw = gridDim.x * 4;
    const ushort* mbase = msg16 + (sub << 3);

    for (int n = gw; n < n_nodes; n += tw) {
        const int beg = offsets[n];
        const int end = offsets[n + 1];     // length is a multiple of 8

        float aE[4] = {0, 0, 0, 0}, aO[4] = {0, 0, 0, 0};

        for (int base = beg; base < end; base += 64) {
            const int m = min(64, end - base);
            const int full = m >> 3;        // 1..8, wave-uniform
            int s[8];
            uint4 v[8];
            #pragma unroll
            for (int j = 0; j < 8; ++j)     // 16B broadcast index loads
                if (j < full) s[j] = (int)sortedG[base + j * 8 + grp];
            #pragma unroll
            for (int j = 0; j < 8; ++j)     // all rows in flight together
                if (j < full) v[j] = *(const uint4*)(mbase + ((size_t)s[j] << 6));
            #pragma unroll
            for (int j = 0; j < 8; ++j)
                if (j < full) { ACC8(v[j], aE, aO); }
        }

        #pragma unroll
        for (int d2 = 0; d2 < 4; ++d2) {    // butterfly over grp (lane bits 3..5)
            aE[d2] += __shfl_xor(aE[d2], 8, 64);
            aO[d2] += __shfl_xor(aO[d2], 8, 64);
            aE[d2] += __shfl_xor(aE[d2], 16, 64);
            aO[d2] += __shfl_xor(aO[d2], 16, 64);
            aE[d2] += __shfl_xor(aE[d2], 32, 64);
            aO[d2] += __shfl_xor(aO[d2], 32, 64);
        }
        if (grp == 0) {                     // 8 lanes x 32B = full 256B row
            float* zr = z + (size_t)n * D + (sub << 3);
            float4 v0 = { aE[0], aO[0], aE[1], aO[1] };
            float4 v1 = { aE[2], aO[2], aE[3], aO[3] };
            *(float4*)zr = v0;
            *(float4*)(zr + 4) = v1;
        }
    }
}

// ---------------------------------------------------------------------------
// K6: update MLP (node-per-lane) z -> d_out
// ---------------------------------------------------------------------------
__global__ __launch_bounds__(256) void k6_mlp_out(
    const float* __restrict__ z,
    const float* __restrict__ U1, const float* __restrict__ c1,
    const float* __restrict__ U2, const float* __restrict__ c2,
    float* __restrict__ out, int N)
{
    const int node = blockIdx.x * 256 + threadIdx.x;
    mlp2_rowlane<false>(z, U1, c1, U2, c2, node, N, nullptr, out);
}

extern "C" void kernel_launch(void* const* d_in, const int* in_sizes, int n_in,
                              void* d_out, int out_size, void* d_ws, size_t ws_size,
                              hipStream_t stream) {
    const float* y  = (const float*)d_in[0];
    const int*  src = (const int*) d_in[1];
    const int*  dst = (const int*) d_in[2];
    const float* W1 = (const float*)d_in[3];
    const float* b1 = (const float*)d_in[4];
    const float* W2 = (const float*)d_in[5];
    const float* b2 = (const float*)d_in[6];
    const float* U1 = (const float*)d_in[7];
    const float* c1 = (const float*)d_in[8];
    const float* U2 = (const float*)d_in[9];
    const float* c2 = (const float*)d_in[10];

    const int N = in_sizes[0] / D;               // 50000
    const int E = in_sizes[1];                   // 1250000
    const int NBA   = (E + CHUNK - 1) / CHUNK;   // 306 partition chunks
    const int NBpad = (N + 255) / 256;           // 196 node chunks == buckets
    const int NMB   = (N + 255) / 256;           // 196 MLP blocks (256 nodes ea)

    // Workspace layout; z aliases the hist/partition scratch (dead by k5).
    char* ws = (char*)d_ws;
    auto al16 = [](size_t x) { return (x + 15) & ~15ull; };
    ushort* msg16 = (ushort*)ws;  ws += al16((size_t)(N + 1) * D * 2);
    int* counts   = (int*)ws;     ws += al16((size_t)N * 4);
    int* offsets  = (int*)ws;     ws += al16((size_t)(N + 1) * 4);
    int* tot      = (int*)ws;     ws += al16(256 * 4);
    int* bsumP    = (int*)ws;     ws += al16(256 * 4);
    ushort* sortedG = (ushort*)ws; ws += al16((size_t)(E + 8 * N) * 2);
    // overlap region (max(histG+startG+packedG, z)):
    float* z      = (float*)ws;                        // N*D floats (12.8 MB)
    int*   histG  = (int*)ws;                          // NBA*256 ints
    int*   startG = histG + (size_t)NBA * 256;         // NBA*256 ints
    uint*  packedG = (uint*)(startG + (size_t)NBA * 256);  // E uints

    hipMemsetAsync(counts, 0, (size_t)N * sizeof(int), stream);

    k1_mlp_hist<<<NBA + NMB, 256, 0, stream>>>(
        y, W1, b1, W2, b2, msg16, N, dst, counts, histG, E, NBA);

    k2_scans<<<256 + NBpad, 256, 0, stream>>>(
        histG, startG, tot, counts, bsumP, N, NBA);

    k3_offsets_scatter<<<NBpad + NBA, 256, 0, stream>>>(
        counts, bsumP, offsets, N, E, NBpad, src, dst, startG, tot, packedG);

    k4_place<<<NBpad, 256, 0, stream>>>(packedG, tot, offsets, sortedG, N);

    k5_gather<<<3200, 256, 0, stream>>>(msg16, offsets, sortedG, z, N);

    k6_mlp_out<<<NMB, 256, 0, stream>>>(z, U1, c1, U2, c2, (float*)d_out, N);
}

// Round 7
// 223.899 us; speedup vs baseline: 1.4875x; 1.4875x over previous
//
#include <hip/hip_runtime.h>

#define D 64
#define CHUNK 4096      // edges per partition block
#define BSHIFT 8        // bucket = dst >> 8 (256 nodes per bucket)

typedef unsigned int uint;
typedef unsigned short ushort;

using bf16x8 = __attribute__((ext_vector_type(8))) short;   // 8 bf16 (4 VGPRs)
using f32x4  = __attribute__((ext_vector_type(4))) float;   // 4 fp32 acc

// fp32 -> bf16 round-to-nearest-even (finite inputs)
__device__ __forceinline__ uint f2bf(float f) {
    uint u = __float_as_uint(f);
    return (u + 0x7fffu + ((u >> 16) & 1u)) >> 16;
}
__device__ __forceinline__ uint pk2(float a, float b) {
    return f2bf(a) | (f2bf(b) << 16);
}

// decode a uint4 (8 packed bf16) and accumulate into even/odd fp32 accs
#define ACC8(v, aE, aO) do {                                                   \
    aE[0] += __uint_as_float((v).x << 16);                                     \
    aO[0] += __uint_as_float((v).x & 0xffff0000u);                             \
    aE[1] += __uint_as_float((v).y << 16);                                     \
    aO[1] += __uint_as_float((v).y & 0xffff0000u);                             \
    aE[2] += __uint_as_float((v).z << 16);                                     \
    aO[2] += __uint_as_float((v).z & 0xffff0000u);                             \
    aE[3] += __uint_as_float((v).w << 16);                                     \
    aO[3] += __uint_as_float((v).w & 0xffff0000u);                             \
} while (0)

// ---------------------------------------------------------------------------
// MFMA 2-layer MLP: each wave computes a 16-node tile of
// out = relu(relu(X@W1+b1)@W2+b2) with 16x16x32 bf16 MFMAs.
// Layouts (HW-verified per guide):
//   A-frag:  lane holds A[m=lane&15][k=quad*8+j], j=0..7   (quad=lane>>4)
//   B-frag:  lane holds B[k=quad*8+j][n=lane&15]
//   C/D:     lane holds D[row=quad*4+reg][col=lane&15]
// H (C-layout) -> A-layout via LDS round-trip (stride 72 shorts: conflict-free).
// ---------------------------------------------------------------------------
template <bool BF16IN, bool BF16OUT>
__global__ __launch_bounds__(256) void mlp_mfma(
    const float* __restrict__ Xf, const ushort* __restrict__ Xb,
    const float* __restrict__ W1, const float* __restrict__ b1v,
    const float* __restrict__ W2, const float* __restrict__ b2v,
    ushort* __restrict__ out16, float* __restrict__ out32, int N)
{
    __shared__ __align__(16) ushort Hs[4][16][72];
    const int lane = threadIdx.x & 63;
    const int wv   = threadIdx.x >> 6;
    const int tile = blockIdx.x * 4 + wv;
    const int m = lane & 15;
    const int q = lane >> 4;

    // ---- weight B-frags (bf16, VGPR-resident) ----
    bf16x8 w1f[4][2], w2f[4][2];
    #pragma unroll
    for (int t = 0; t < 4; ++t) {
        const int n = t * 16 + m;
        #pragma unroll
        for (int kf = 0; kf < 2; ++kf) {
            bf16x8 f1, f2;
            #pragma unroll
            for (int j = 0; j < 8; ++j) {
                const int k = kf * 32 + q * 8 + j;
                f1[j] = (short)f2bf(W1[k * D + n]);
                f2[j] = (short)f2bf(W2[k * D + n]);
            }
            w1f[t][kf] = f1;
            w2f[t][kf] = f2;
        }
    }

    // ---- X A-frags ----
    const int rowbase = tile * 16;
    int r = rowbase + m;
    if (r >= N) r = N - 1;                 // clamp: loads only, stores predicated
    bf16x8 ax0, ax1;
    if (BF16IN) {
        const ushort* xr = Xb + (size_t)r * D + q * 8;
        ax0 = *(const bf16x8*)xr;          // k = q*8 + j
        ax1 = *(const bf16x8*)(xr + 32);   // k = 32 + q*8 + j
    } else {
        const float* xr = Xf + (size_t)r * D + q * 8;
        float4 x0 = *(const float4*)xr;
        float4 x1 = *(const float4*)(xr + 4);
        float4 x2 = *(const float4*)(xr + 32);
        float4 x3 = *(const float4*)(xr + 36);
        ax0[0]=(short)f2bf(x0.x); ax0[1]=(short)f2bf(x0.y);
        ax0[2]=(short)f2bf(x0.z); ax0[3]=(short)f2bf(x0.w);
        ax0[4]=(short)f2bf(x1.x); ax0[5]=(short)f2bf(x1.y);
        ax0[6]=(short)f2bf(x1.z); ax0[7]=(short)f2bf(x1.w);
        ax1[0]=(short)f2bf(x2.x); ax1[1]=(short)f2bf(x2.y);
        ax1[2]=(short)f2bf(x2.z); ax1[3]=(short)f2bf(x2.w);
        ax1[4]=(short)f2bf(x3.x); ax1[5]=(short)f2bf(x3.y);
        ax1[6]=(short)f2bf(x3.z); ax1[7]=(short)f2bf(x3.w);
    }

    const f32x4 zero4 = {0.f, 0.f, 0.f, 0.f};
    f32x4 acc[4];

    // ---- layer 1 ----
    #pragma unroll
    for (int t = 0; t < 4; ++t) acc[t] = zero4;
    #pragma unroll
    for (int t = 0; t < 4; ++t) {
        acc[t] = __builtin_amdgcn_mfma_f32_16x16x32_bf16(ax0, w1f[t][0], acc[t], 0, 0, 0);
        acc[t] = __builtin_amdgcn_mfma_f32_16x16x32_bf16(ax1, w1f[t][1], acc[t], 0, 0, 0);
    }
    #pragma unroll
    for (int t = 0; t < 4; ++t) {
        const float bv = b1v[t * 16 + m];
        #pragma unroll
        for (int rg = 0; rg < 4; ++rg) {
            float hv = fmaxf(acc[t][rg] + bv, 0.f);
            Hs[wv][q * 4 + rg][t * 16 + m] = (ushort)f2bf(hv);
        }
    }
    __syncthreads();   // single pass, all waves execute: intra-wave RAW safe

    // ---- H C-layout -> A-frags ----
    bf16x8 ah0 = *(const bf16x8*)&Hs[wv][m][q * 8];
    bf16x8 ah1 = *(const bf16x8*)&Hs[wv][m][32 + q * 8];

    // ---- layer 2 ----
    #pragma unroll
    for (int t = 0; t < 4; ++t) acc[t] = zero4;
    #pragma unroll
    for (int t = 0; t < 4; ++t) {
        acc[t] = __builtin_amdgcn_mfma_f32_16x16x32_bf16(ah0, w2f[t][0], acc[t], 0, 0, 0);
        acc[t] = __builtin_amdgcn_mfma_f32_16x16x32_bf16(ah1, w2f[t][1], acc[t], 0, 0, 0);
    }
    #pragma unroll
    for (int t = 0; t < 4; ++t) {
        const float bv = b2v[t * 16 + m];
        #pragma unroll
        for (int rg = 0; rg < 4; ++rg) {
            const int row = rowbase + q * 4 + rg;
            if (row < N) {
                float ov = fmaxf(acc[t][rg] + bv, 0.f);
                if (BF16OUT) out16[(size_t)row * D + t * 16 + m] = (ushort)f2bf(ov);
                else         out32[(size_t)row * D + t * 16 + m] = ov;
            }
        }
    }
}

// ---------------------------------------------------------------------------
// K1: per-chunk bucket histogram + global per-node histogram. Block 0 also
// zeroes msg row N (the pad target row).
// ---------------------------------------------------------------------------
__global__ __launch_bounds__(256) void k1_hist(
    const int* __restrict__ dst, int* __restrict__ counts,
    int* __restrict__ histG, int E, ushort* __restrict__ msg16, int N)
{
    __shared__ int lhist[256];
    const int t = threadIdx.x;
    if (blockIdx.x == 0 && t < D) msg16[(size_t)N * D + t] = 0;
    lhist[t] = 0;
    __syncthreads();
    const int cbase = blockIdx.x * CHUNK;
    for (int j = t; j < CHUNK; j += 256) {
        int e = cbase + j;
        if (e < E) {
            int d = dst[e];
            atomicAdd(&lhist[d >> BSHIFT], 1);
            atomicAdd(&counts[d], 1);
        }
    }
    __syncthreads();
    histG[blockIdx.x * 256 + t] = lhist[t];
}

// ---------------------------------------------------------------------------
// K2: blocks [0,256): per-bucket scan over chunk histograms -> startG, tot.
//     blocks [256,256+NBpad): per-chunk sums of PADDED node counts -> bsumP.
// ---------------------------------------------------------------------------
__global__ __launch_bounds__(256) void k2_scans(
    const int* __restrict__ histG, int* __restrict__ startG,
    int* __restrict__ tot,
    const int* __restrict__ counts, int* __restrict__ bsumP,
    int N, int NBA)
{
    __shared__ int tmp[256];
    const int t = threadIdx.x;
    if (blockIdx.x < 256) {
        const int b = blockIdx.x;
        const int i0 = 2 * t, i1 = 2 * t + 1;
        int v0 = (i0 < NBA) ? histG[i0 * 256 + b] : 0;
        int v1 = (i1 < NBA) ? histG[i1 * 256 + b] : 0;
        int s = v0 + v1;
        int x = s; tmp[t] = x; __syncthreads();
        #pragma unroll
        for (int off = 1; off < 256; off <<= 1) {
            int add = (t >= off) ? tmp[t - off] : 0; __syncthreads();
            x += add; tmp[t] = x; __syncthreads();
        }
        int excl = x - s;
        if (i0 < NBA) startG[i0 * 256 + b] = excl;
        if (i1 < NBA) startG[i1 * 256 + b] = excl + v0;
        if (t == 255) tot[b] = x;
    } else {
        const int blk = blockIdx.x - 256;
        int i = blk * 256 + t;
        int c = (i < N) ? counts[i] : 0;
        int p = (c + 7) & ~7;   // padded to multiple of 8
        #pragma unroll
        for (int off = 32; off > 0; off >>= 1) p += __shfl_down(p, off, 64);
        if ((t & 63) == 0) tmp[t >> 6] = p;
        __syncthreads();
        if (t == 0) bsumP[blk] = tmp[0] + tmp[1] + tmp[2] + tmp[3];
    }
}

// ---------------------------------------------------------------------------
// K3: blocks [0,NBpad): padded exclusive scan -> offsets[] (+offsets[N]).
//     blocks [NBpad, NBpad+NBA): partition edges into bucket-grouped packedG.
// ---------------------------------------------------------------------------
__global__ __launch_bounds__(256) void k3_offsets_scatter(
    const int* __restrict__ counts, const int* __restrict__ bsumP,
    int* __restrict__ offsets, int N, int E, int NBpad,
    const int* __restrict__ src, const int* __restrict__ dst,
    const int* __restrict__ startG, const int* __restrict__ tot,
    uint* __restrict__ packedG)
{
    __shared__ int t1[256];
    __shared__ int t2[256];
    const int t = threadIdx.x;
    if ((int)blockIdx.x < NBpad) {
        int bx = (t < NBpad) ? bsumP[t] : 0;
        int x1 = bx; t1[t] = x1; __syncthreads();
        #pragma unroll
        for (int off = 1; off < 256; off <<= 1) {
            int add = (t >= off) ? t1[t - off] : 0; __syncthreads();
            x1 += add; t1[t] = x1; __syncthreads();
        }
        const int base = (blockIdx.x == 0) ? 0 : t1[blockIdx.x - 1];
        const int i = blockIdx.x * 256 + t;
        int c = (i < N) ? counts[i] : 0;
        int p = (c + 7) & ~7;
        int x2 = p; t2[t] = x2; __syncthreads();
        #pragma unroll
        for (int off = 1; off < 256; off <<= 1) {
            int add = (t >= off) ? t2[t - off] : 0; __syncthreads();
            x2 += add; t2[t] = x2; __syncthreads();
        }
        int excl = x2 - p + base;
        if (i < N) offsets[i] = excl;
        if (blockIdx.x == 0 && t == 0) offsets[N] = t1[NBpad - 1];
    } else {
        const int blk = blockIdx.x - NBpad;
        int tv = tot[t];
        int x = tv; t1[t] = x; __syncthreads();
        #pragma unroll
        for (int off = 1; off < 256; off <<= 1) {
            int add = (t >= off) ? t1[t - off] : 0; __syncthreads();
            x += add; t1[t] = x; __syncthreads();
        }
        t2[t] = (x - tv) + startG[blk * 256 + t];   // cursor per bucket
        __syncthreads();
        const int cbase = blk * CHUNK;
        for (int j = t; j < CHUNK; j += 256) {
            int e = cbase + j;
            if (e < E) {
                int s = src[e], d = dst[e];
                int pos = atomicAdd(&t2[d >> BSHIFT], 1);
                packedG[pos] = ((uint)(d & 255) << 16) | (uint)s;
            }
        }
    }
}

// ---------------------------------------------------------------------------
// K4: one block per bucket: place packed entries at final padded positions
// (single-writer region -> L2 merges 2B writes), fill padding with row N.
// ---------------------------------------------------------------------------
__global__ __launch_bounds__(256) void k4_place(
    const uint* __restrict__ packedG, const int* __restrict__ tot,
    const int* __restrict__ offsets,
    ushort* __restrict__ sortedG, int N)
{
    __shared__ int t1[256];
    __shared__ int sbase[256];
    __shared__ int cur[256];
    __shared__ int nxt[256];
    const int t = threadIdx.x;
    const int b = blockIdx.x;

    int tv = tot[t];
    int x = tv; t1[t] = x; __syncthreads();
    #pragma unroll
    for (int off = 1; off < 256; off <<= 1) {
        int add = (t >= off) ? t1[t - off] : 0; __syncthreads();
        x += add; t1[t] = x; __syncthreads();
    }
    sbase[t] = x - tv;
    const int node = b * 256 + t;
    cur[t] = (node < N) ? offsets[node] : 0;
    nxt[t] = (node < N) ? offsets[node + 1] : 0;
    __syncthreads();

    const int base_pk = sbase[b];
    const int cnt = tot[b];
    for (int i = t; i < cnt; i += 256) {
        uint e = packedG[base_pk + i];
        int dloc = e >> 16;
        int p = atomicAdd(&cur[dloc], 1);
        sortedG[p] = (ushort)(e & 0xffffu);
    }
    __syncthreads();
    if (node < N) {
        const ushort zr = (ushort)N;
        for (int p = cur[t]; p < nxt[t]; ++p) sortedG[p] = zr;  // <=7 pads
    }
}

// ---------------------------------------------------------------------------
// K5: gather segment-sum (bf16 msg, padded CSR) -> z bf16.
// lane = (grp, sub): grp=lane>>3 picks the edge, sub=lane&7 picks 16B of the
// 128B row. All <=8 row loads of a batch issued before any decode.
// ---------------------------------------------------------------------------
__global__ __launch_bounds__(256) void k5_gather(
    const ushort* __restrict__ msg16,
    const int* __restrict__ offsets, const ushort* __restrict__ sortedG,
    ushort* __restrict__ z16, int n_nodes)
{
    const int lane = threadIdx.x & 63;
    const int sub = lane & 7;
    const int grp = lane >> 3;
    const int gw = blockIdx.x * 4 + (threadIdx.x >> 6);
    const int tw = gridDim.x * 4;
    const ushort* mbase = msg16 + (sub << 3);

    for (int n = gw; n < n_nodes; n += tw) {
        const int beg = offsets[n];
        const int end = offsets[n + 1];     // length is a multiple of 8

        float aE[4] = {0, 0, 0, 0}, aO[4] = {0, 0, 0, 0};

        for (int base = beg; base < end; base += 64) {
            const int m = min(64, end - base);
            const int full = m >> 3;        // 1..8, wave-uniform
            int s[8];
            uint4 v[8];
            #pragma unroll
            for (int j = 0; j < 8; ++j)
                if (j < full) s[j] = (int)sortedG[base + j * 8 + grp];
            #pragma unroll
            for (int j = 0; j < 8; ++j)     // all rows in flight together
                if (j < full) v[j] = *(const uint4*)(mbase + ((size_t)s[j] << 6));
            #pragma unroll
            for (int j = 0; j < 8; ++j)
                if (j < full) { ACC8(v[j], aE, aO); }
        }

        #pragma unroll
        for (int d2 = 0; d2 < 4; ++d2) {    // butterfly over grp (lane bits 3..5)
            aE[d2] += __shfl_xor(aE[d2], 8, 64);
            aO[d2] += __shfl_xor(aO[d2], 8, 64);
            aE[d2] += __shfl_xor(aE[d2], 16, 64);
            aO[d2] += __shfl_xor(aO[d2], 16, 64);
            aE[d2] += __shfl_xor(aE[d2], 32, 64);
            aO[d2] += __shfl_xor(aO[d2], 32, 64);
        }
        if (grp == 0) {                     // 8 lanes x 16B = full 128B bf16 row
            uint4 pv;
            pv.x = pk2(aE[0], aO[0]);
            pv.y = pk2(aE[1], aO[1]);
            pv.z = pk2(aE[2], aO[2]);
            pv.w = pk2(aE[3], aO[3]);
            *(uint4*)(z16 + (size_t)n * D + (sub << 3)) = pv;
        }
    }
}

extern "C" void kernel_launch(void* const* d_in, const int* in_sizes, int n_in,
                              void* d_out, int out_size, void* d_ws, size_t ws_size,
                              hipStream_t stream) {
    const float* y  = (const float*)d_in[0];
    const int*  src = (const int*) d_in[1];
    const int*  dst = (const int*) d_in[2];
    const float* W1 = (const float*)d_in[3];
    const float* b1 = (const float*)d_in[4];
    const float* W2 = (const float*)d_in[5];
    const float* b2 = (const float*)d_in[6];
    const float* U1 = (const float*)d_in[7];
    const float* c1 = (const float*)d_in[8];
    const float* U2 = (const float*)d_in[9];
    const float* c2 = (const float*)d_in[10];

    const int N = in_sizes[0] / D;               // 50000
    const int E = in_sizes[1];                   // 1250000
    const int NBA   = (E + CHUNK - 1) / CHUNK;   // 306 partition chunks
    const int NBpad = (N + 255) / 256;           // 196 node chunks == buckets
    const int NT    = (N + 15) / 16;             // 3125 MFMA row-tiles
    const int MB    = (NT + 3) / 4;              // 782 MLP blocks (4 waves ea)

    // Workspace layout; z16 aliases the hist/partition scratch (dead by k5).
    char* ws = (char*)d_ws;
    auto al16 = [](size_t x) { return (x + 15) & ~15ull; };
    ushort* msg16 = (ushort*)ws;  ws += al16((size_t)(N + 1) * D * 2);
    int* counts   = (int*)ws;     ws += al16((size_t)N * 4);
    int* offsets  = (int*)ws;     ws += al16((size_t)(N + 1) * 4);
    int* tot      = (int*)ws;     ws += al16(256 * 4);
    int* bsumP    = (int*)ws;     ws += al16(256 * 4);
    ushort* sortedG = (ushort*)ws; ws += al16((size_t)(E + 8 * N) * 2);
    // overlap region: max(histG+startG+packedG, z16)
    ushort* z16   = (ushort*)ws;                       // N*D bf16 (6.4 MB)
    int*   histG  = (int*)ws;                          // NBA*256 ints
    int*   startG = histG + (size_t)NBA * 256;         // NBA*256 ints
    uint*  packedG = (uint*)(startG + (size_t)NBA * 256);  // E uints

    hipMemsetAsync(counts, 0, (size_t)N * sizeof(int), stream);

    // stage-1 MLP (MFMA): y fp32 -> msg16 bf16
    mlp_mfma<false, true><<<MB, 256, 0, stream>>>(
        y, nullptr, W1, b1, W2, b2, msg16, nullptr, N);

    k1_hist<<<NBA, 256, 0, stream>>>(dst, counts, histG, E, msg16, N);

    k2_scans<<<256 + NBpad, 256, 0, stream>>>(
        histG, startG, tot, counts, bsumP, N, NBA);

    k3_offsets_scatter<<<NBpad + NBA, 256, 0, stream>>>(
        counts, bsumP, offsets, N, E, NBpad, src, dst, startG, tot, packedG);

    k4_place<<<NBpad, 256, 0, stream>>>(packedG, tot, offsets, sortedG, N);

    k5_gather<<<3200, 256, 0, stream>>>(msg16, offsets, sortedG, z16, N);

    // stage-2 MLP (MFMA): z16 bf16 -> out fp32
    mlp_mfma<true, false><<<MB, 256, 0, stream>>>(
        nullptr, z16, U1, c1, U2, c2, nullptr, (float*)d_out, N);
}

// Round 8
// 166.654 us; speedup vs baseline: 1.9985x; 1.3435x over previous
//
#include <hip/hip_runtime.h>

#define D 64
#define CHUNK 8192      // edges per partition block
#define BSHIFT 8        // bucket = dst >> 8 (256 nodes per bucket)

typedef unsigned int uint;
typedef unsigned short ushort;

using bf16x8 = __attribute__((ext_vector_type(8))) short;   // 8 bf16 (4 VGPRs)
using f32x4  = __attribute__((ext_vector_type(4))) float;   // 4 fp32 acc

// fp32 -> bf16 round-to-nearest-even (finite inputs)
__device__ __forceinline__ uint f2bf(float f) {
    uint u = __float_as_uint(f);
    return (u + 0x7fffu + ((u >> 16) & 1u)) >> 16;
}
__device__ __forceinline__ uint pk2(float a, float b) {
    return f2bf(a) | (f2bf(b) << 16);
}

// decode a uint4 (8 packed bf16) and accumulate into even/odd fp32 accs
#define ACC8(v, aE, aO) do {                                                   \
    aE[0] += __uint_as_float((v).x << 16);                                     \
    aO[0] += __uint_as_float((v).x & 0xffff0000u);                             \
    aE[1] += __uint_as_float((v).y << 16);                                     \
    aO[1] += __uint_as_float((v).y & 0xffff0000u);                             \
    aE[2] += __uint_as_float((v).z << 16);                                     \
    aO[2] += __uint_as_float((v).z & 0xffff0000u);                             \
    aE[3] += __uint_as_float((v).w << 16);                                     \
    aO[3] += __uint_as_float((v).w & 0xffff0000u);                             \
} while (0)

// masked variant: acc += mk * decode(v)
#define ACC8M(v, aE, aO, mk) do {                                              \
    aE[0] = fmaf(mk, __uint_as_float((v).x << 16), aE[0]);                     \
    aO[0] = fmaf(mk, __uint_as_float((v).x & 0xffff0000u), aO[0]);             \
    aE[1] = fmaf(mk, __uint_as_float((v).y << 16), aE[1]);                     \
    aO[1] = fmaf(mk, __uint_as_float((v).y & 0xffff0000u), aO[1]);             \
    aE[2] = fmaf(mk, __uint_as_float((v).z << 16), aE[2]);                     \
    aO[2] = fmaf(mk, __uint_as_float((v).z & 0xffff0000u), aO[2]);             \
    aE[3] = fmaf(mk, __uint_as_float((v).w << 16), aE[3]);                     \
    aO[3] = fmaf(mk, __uint_as_float((v).w & 0xffff0000u), aO[3]);             \
} while (0)

// ---------------------------------------------------------------------------
// MFMA 2-layer MLP tile: one wave computes 16 nodes of
// out = relu(relu(X@W1+b1)@W2+b2) with 16x16x32 bf16 MFMAs.
//   A-frag:  lane holds A[m=lane&15][k=quad*8+j]
//   B-frag:  lane holds B[k=quad*8+j][n=lane&15]
//   C/D:     lane holds D[row=quad*4+reg][col=lane&15]
// H C->A layout via LDS (stride 72 shorts: conflict-free).
// ---------------------------------------------------------------------------
template <bool BF16IN, bool BF16OUT>
__device__ __forceinline__ void mlp_tile(
    int tile, ushort (*Hs)[72],
    const float* __restrict__ Xf, const ushort* __restrict__ Xb,
    const float* __restrict__ W1, const float* __restrict__ b1v,
    const float* __restrict__ W2, const float* __restrict__ b2v,
    ushort* __restrict__ out16, float* __restrict__ out32, int N)
{
    const int lane = threadIdx.x & 63;
    const int m = lane & 15;
    const int q = lane >> 4;

    // weight B-frags (bf16, VGPR-resident)
    bf16x8 w1f[4][2], w2f[4][2];
    #pragma unroll
    for (int t = 0; t < 4; ++t) {
        const int n = t * 16 + m;
        #pragma unroll
        for (int kf = 0; kf < 2; ++kf) {
            bf16x8 f1, f2;
            #pragma unroll
            for (int j = 0; j < 8; ++j) {
                const int k = kf * 32 + q * 8 + j;
                f1[j] = (short)f2bf(W1[k * D + n]);
                f2[j] = (short)f2bf(W2[k * D + n]);
            }
            w1f[t][kf] = f1;
            w2f[t][kf] = f2;
        }
    }

    // X A-frags
    const int rowbase = tile * 16;
    int r = rowbase + m;
    if (r >= N) r = N - 1;               // clamp loads; stores predicated
    bf16x8 ax0, ax1;
    if (BF16IN) {
        const ushort* xr = Xb + (size_t)r * D + q * 8;
        ax0 = *(const bf16x8*)xr;
        ax1 = *(const bf16x8*)(xr + 32);
    } else {
        const float* xr = Xf + (size_t)r * D + q * 8;
        float4 x0 = *(const float4*)xr;
        float4 x1 = *(const float4*)(xr + 4);
        float4 x2 = *(const float4*)(xr + 32);
        float4 x3 = *(const float4*)(xr + 36);
        ax0[0]=(short)f2bf(x0.x); ax0[1]=(short)f2bf(x0.y);
        ax0[2]=(short)f2bf(x0.z); ax0[3]=(short)f2bf(x0.w);
        ax0[4]=(short)f2bf(x1.x); ax0[5]=(short)f2bf(x1.y);
        ax0[6]=(short)f2bf(x1.z); ax0[7]=(short)f2bf(x1.w);
        ax1[0]=(short)f2bf(x2.x); ax1[1]=(short)f2bf(x2.y);
        ax1[2]=(short)f2bf(x2.z); ax1[3]=(short)f2bf(x2.w);
        ax1[4]=(short)f2bf(x3.x); ax1[5]=(short)f2bf(x3.y);
        ax1[6]=(short)f2bf(x3.z); ax1[7]=(short)f2bf(x3.w);
    }

    const f32x4 zero4 = {0.f, 0.f, 0.f, 0.f};
    f32x4 acc[4];

    // layer 1
    #pragma unroll
    for (int t = 0; t < 4; ++t) acc[t] = zero4;
    #pragma unroll
    for (int t = 0; t < 4; ++t) {
        acc[t] = __builtin_amdgcn_mfma_f32_16x16x32_bf16(ax0, w1f[t][0], acc[t], 0, 0, 0);
        acc[t] = __builtin_amdgcn_mfma_f32_16x16x32_bf16(ax1, w1f[t][1], acc[t], 0, 0, 0);
    }
    #pragma unroll
    for (int t = 0; t < 4; ++t) {
        const float bv = b1v[t * 16 + m];
        #pragma unroll
        for (int rg = 0; rg < 4; ++rg) {
            float hv = fmaxf(acc[t][rg] + bv, 0.f);
            Hs[q * 4 + rg][t * 16 + m] = (ushort)f2bf(hv);
        }
    }
    __syncthreads();

    // H C-layout -> A-frags
    bf16x8 ah0 = *(const bf16x8*)&Hs[m][q * 8];
    bf16x8 ah1 = *(const bf16x8*)&Hs[m][32 + q * 8];

    // layer 2
    #pragma unroll
    for (int t = 0; t < 4; ++t) acc[t] = zero4;
    #pragma unroll
    for (int t = 0; t < 4; ++t) {
        acc[t] = __builtin_amdgcn_mfma_f32_16x16x32_bf16(ah0, w2f[t][0], acc[t], 0, 0, 0);
        acc[t] = __builtin_amdgcn_mfma_f32_16x16x32_bf16(ah1, w2f[t][1], acc[t], 0, 0, 0);
    }
    #pragma unroll
    for (int t = 0; t < 4; ++t) {
        const float bv = b2v[t * 16 + m];
        #pragma unroll
        for (int rg = 0; rg < 4; ++rg) {
            const int row = rowbase + q * 4 + rg;
            if (row < N) {
                float ov = fmaxf(acc[t][rg] + bv, 0.f);
                if (BF16OUT) out16[(size_t)row * D + t * 16 + m] = (ushort)f2bf(ov);
                else         out32[(size_t)row * D + t * 16 + m] = ov;
            }
        }
    }
}

// ---------------------------------------------------------------------------
// kA: blocks [0,NBA): per-chunk bucket histogram (LDS only, no global atomics)
//     blocks [NBA,...): message MLP (MFMA), msg stored bf16.
// ---------------------------------------------------------------------------
__global__ __launch_bounds__(256) void kA_mlp_hist(
    const float* __restrict__ y,
    const float* __restrict__ W1, const float* __restrict__ b1,
    const float* __restrict__ W2, const float* __restrict__ b2,
    ushort* __restrict__ msg16, int N,
    const int* __restrict__ dst, int* __restrict__ histG, int E, int NBA)
{
    __shared__ __align__(16) ushort Hs[4][16][72];
    __shared__ int lhist[256];
    const int t = threadIdx.x;
    if ((int)blockIdx.x < NBA) {
        lhist[t] = 0;
        __syncthreads();
        const int cbase = blockIdx.x * CHUNK;
        const int lim = min(CHUNK, E - cbase);
        for (int j = t; j < lim; j += 256)
            atomicAdd(&lhist[(uint)dst[cbase + j] >> BSHIFT], 1);
        __syncthreads();
        histG[blockIdx.x * 256 + t] = lhist[t];
    } else {
        const int tile = (blockIdx.x - NBA) * 4 + (t >> 6);
        mlp_tile<false, true>(tile, Hs[t >> 6], y, nullptr, W1, b1, W2, b2,
                              msg16, nullptr, N);
    }
}

// ---------------------------------------------------------------------------
// kB: one block per bucket: exclusive scan over the NBA chunk histograms
//     -> startG[(chunk,bucket)], tot[bucket].
// ---------------------------------------------------------------------------
__global__ __launch_bounds__(256) void kB_scan(
    const int* __restrict__ histG, int* __restrict__ startG,
    int* __restrict__ tot, int NBA)
{
    __shared__ int tmp[256];
    const int t = threadIdx.x;
    const int b = blockIdx.x;
    const int i0 = 2 * t, i1 = 2 * t + 1;
    int v0 = (i0 < NBA) ? histG[i0 * 256 + b] : 0;
    int v1 = (i1 < NBA) ? histG[i1 * 256 + b] : 0;
    int s = v0 + v1;
    int x = s; tmp[t] = x; __syncthreads();
    #pragma unroll
    for (int off = 1; off < 256; off <<= 1) {
        int add = (t >= off) ? tmp[t - off] : 0; __syncthreads();
        x += add; tmp[t] = x; __syncthreads();
    }
    int excl = x - s;
    if (i0 < NBA) startG[i0 * 256 + b] = excl;
    if (i1 < NBA) startG[i1 * 256 + b] = excl + v0;
    if (t == 255) tot[b] = x;
}

// ---------------------------------------------------------------------------
// kC: partition edges into bucket-grouped packedG. Each block scans tot in
// LDS for bucket bases, then scatters its chunk at per-(chunk,bucket) runs.
// ---------------------------------------------------------------------------
__global__ __launch_bounds__(256) void kC_partition(
    const int* __restrict__ src, const int* __restrict__ dst,
    const int* __restrict__ startG, const int* __restrict__ tot,
    uint* __restrict__ packedG, int E)
{
    __shared__ int t1[256];
    __shared__ int cur[256];
    const int t = threadIdx.x;
    int tv = tot[t];
    int x = tv; t1[t] = x; __syncthreads();
    #pragma unroll
    for (int off = 1; off < 256; off <<= 1) {
        int add = (t >= off) ? t1[t - off] : 0; __syncthreads();
        x += add; t1[t] = x; __syncthreads();
    }
    cur[t] = (x - tv) + startG[blockIdx.x * 256 + t];
    __syncthreads();
    const int cbase = blockIdx.x * CHUNK;
    const int lim = min(CHUNK, E - cbase);
    for (int j = t; j < lim; j += 256) {
        const int e = cbase + j;
        int s = src[e], d = dst[e];
        int pos = atomicAdd(&cur[d >> BSHIFT], 1);
        packedG[pos] = ((uint)(d & 255) << 16) | (uint)s;
    }
}

// ---------------------------------------------------------------------------
// kF: one block per bucket. Pass 1: per-node counts via LDS atomics.
// Scan -> local offsets; write absolute offsets[node]. Pass 2: place entries
// node-grouped into sortedG (single-writer bucket region -> L2 merges).
// ---------------------------------------------------------------------------
__global__ __launch_bounds__(256) void kF_place(
    const uint* __restrict__ packedG, const int* __restrict__ tot,
    ushort* __restrict__ sortedG, int* __restrict__ offsets, int N, int E)
{
    __shared__ int t1[256];
    __shared__ int cnt[256];
    __shared__ int cur[256];
    const int t = threadIdx.x;
    const int b = blockIdx.x;

    int tv = tot[t];
    int x = tv; t1[t] = x; __syncthreads();
    #pragma unroll
    for (int off = 1; off < 256; off <<= 1) {
        int add = (t >= off) ? t1[t - off] : 0; __syncthreads();
        x += add; t1[t] = x; __syncthreads();
    }
    const int pbase = (b == 0) ? 0 : t1[b - 1];
    const int cn = tot[b];

    cnt[t] = 0;
    __syncthreads();
    for (int i = t; i < cn; i += 256)
        atomicAdd(&cnt[packedG[pbase + i] >> 16], 1);
    __syncthreads();

    int c = cnt[t];
    int x2 = c; t1[t] = x2; __syncthreads();
    #pragma unroll
    for (int off = 1; off < 256; off <<= 1) {
        int add = (t >= off) ? t1[t - off] : 0; __syncthreads();
        x2 += add; t1[t] = x2; __syncthreads();
    }
    const int excl = x2 - c;
    cur[t] = pbase + excl;
    const int node = b * 256 + t;
    if (node < N) offsets[node] = pbase + excl;
    if (b == 0 && t == 0) offsets[N] = E;
    __syncthreads();

    for (int i = t; i < cn; i += 256) {
        uint e = packedG[pbase + i];
        int p = atomicAdd(&cur[e >> 16], 1);
        sortedG[p] = (ushort)(e & 0xffffu);
    }
}

// ---------------------------------------------------------------------------
// k5: gather segment-sum (bf16 msg, unpadded CSR) -> z bf16.
// lane=(grp,sub): grp=lane>>3 picks the edge, sub=lane&7 picks 16B of the
// 128B row. All row loads of a batch issued before any decode. Remainder
// step clamps masked groups to the last entry (same line -> ~free).
// ---------------------------------------------------------------------------
__global__ __launch_bounds__(256) void k5_gather(
    const ushort* __restrict__ msg16,
    const int* __restrict__ offsets, const ushort* __restrict__ sortedG,
    ushort* __restrict__ z16, int n_nodes)
{
    const int lane = threadIdx.x & 63;
    const int sub = lane & 7;
    const int grp = lane >> 3;
    const int gw = blockIdx.x * 4 + (threadIdx.x >> 6);
    const int tw = gridDim.x * 4;
    const ushort* mbase = msg16 + (sub << 3);

    for (int n = gw; n < n_nodes; n += tw) {
        const int beg = offsets[n];
        const int end = offsets[n + 1];

        float aE[4] = {0, 0, 0, 0}, aO[4] = {0, 0, 0, 0};

        for (int base = beg; base < end; base += 64) {
            const int m = min(64, end - base);
            const int full = m >> 3;        // 0..8, wave-uniform
            const int rem = m & 7;
            int s[8];
            #pragma unroll
            for (int j = 0; j < 8; ++j)
                if (j < full) s[j] = (int)sortedG[base + j * 8 + grp];
            int srem = 0;
            if (rem) srem = (int)sortedG[base + min(full * 8 + grp, m - 1)];
            uint4 v[8];
            #pragma unroll
            for (int j = 0; j < 8; ++j)
                if (j < full) v[j] = *(const uint4*)(mbase + ((size_t)s[j] << 6));
            uint4 vr;
            if (rem) vr = *(const uint4*)(mbase + ((size_t)srem << 6));
            #pragma unroll
            for (int j = 0; j < 8; ++j)
                if (j < full) { ACC8(v[j], aE, aO); }
            if (rem) {
                const float mk = (grp < rem) ? 1.f : 0.f;
                ACC8M(vr, aE, aO, mk);
            }
        }

        #pragma unroll
        for (int d2 = 0; d2 < 4; ++d2) {    // butterfly over grp (lane bits 3..5)
            aE[d2] += __shfl_xor(aE[d2], 8, 64);
            aO[d2] += __shfl_xor(aO[d2], 8, 64);
            aE[d2] += __shfl_xor(aE[d2], 16, 64);
            aO[d2] += __shfl_xor(aO[d2], 16, 64);
            aE[d2] += __shfl_xor(aE[d2], 32, 64);
            aO[d2] += __shfl_xor(aO[d2], 32, 64);
        }
        if (grp == 0) {                     // 8 lanes x 16B = full 128B row
            uint4 pv;
            pv.x = pk2(aE[0], aO[0]);
            pv.y = pk2(aE[1], aO[1]);
            pv.z = pk2(aE[2], aO[2]);
            pv.w = pk2(aE[3], aO[3]);
            *(uint4*)(z16 + (size_t)n * D + (sub << 3)) = pv;
        }
    }
}

// ---------------------------------------------------------------------------
// mlp2: update MLP (MFMA): z16 bf16 -> out fp32
// ---------------------------------------------------------------------------
__global__ __launch_bounds__(256) void k_mlp2(
    const ushort* __restrict__ z16,
    const float* __restrict__ U1, const float* __restrict__ c1,
    const float* __restrict__ U2, const float* __restrict__ c2,
    float* __restrict__ out, int N)
{
    __shared__ __align__(16) ushort Hs[4][16][72];
    const int tile = blockIdx.x * 4 + (threadIdx.x >> 6);
    mlp_tile<true, false>(tile, Hs[threadIdx.x >> 6], nullptr, z16,
                          U1, c1, U2, c2, nullptr, out, N);
}

extern "C" void kernel_launch(void* const* d_in, const int* in_sizes, int n_in,
                              void* d_out, int out_size, void* d_ws, size_t ws_size,
                              hipStream_t stream) {
    const float* y  = (const float*)d_in[0];
    const int*  src = (const int*) d_in[1];
    const int*  dst = (const int*) d_in[2];
    const float* W1 = (const float*)d_in[3];
    const float* b1 = (const float*)d_in[4];
    const float* W2 = (const float*)d_in[5];
    const float* b2 = (const float*)d_in[6];
    const float* U1 = (const float*)d_in[7];
    const float* c1 = (const float*)d_in[8];
    const float* U2 = (const float*)d_in[9];
    const float* c2 = (const float*)d_in[10];

    const int N = in_sizes[0] / D;               // 50000
    const int E = in_sizes[1];                   // 1250000
    const int NBA   = (E + CHUNK - 1) / CHUNK;   // 153 partition chunks
    const int NBUCK = (N + 255) / 256;           // 196 buckets
    const int NT    = (N + 15) / 16;             // 3125 MFMA row-tiles
    const int MB    = (NT + 3) / 4;              // 782 MLP blocks

    // Workspace layout (z16 aliases hist/partition scratch, dead by k5)
    char* ws = (char*)d_ws;
    auto al16 = [](size_t x) { return (x + 15) & ~15ull; };
    ushort* msg16   = (ushort*)ws;  ws += al16((size_t)N * D * 2);
    int*    offsets = (int*)ws;     ws += al16((size_t)(N + 1) * 4);
    int*    tot     = (int*)ws;     ws += al16(256 * 4);
    ushort* sortedG = (ushort*)ws;  ws += al16((size_t)E * 2);
    // overlap region: max(histG+startG+packedG, z16)
    ushort* z16     = (ushort*)ws;                     // N*D bf16 (6.4 MB)
    int*    histG   = (int*)ws;                        // NBA*256 ints
    int*    startG  = histG + (size_t)NBA * 256;
    uint*   packedG = (uint*)(startG + (size_t)NBA * 256);  // E uints

    // 1) fused: message MLP (MFMA) + per-chunk bucket histogram
    kA_mlp_hist<<<NBA + MB, 256, 0, stream>>>(
        y, W1, b1, W2, b2, msg16, N, dst, histG, E, NBA);

    // 2) per-bucket scan over chunk histograms
    kB_scan<<<256, 256, 0, stream>>>(histG, startG, tot, NBA);

    // 3) partition edges into bucket-grouped packedG
    kC_partition<<<NBA, 256, 0, stream>>>(src, dst, startG, tot, packedG, E);

    // 4) per-bucket counting sort -> sortedG + absolute offsets
    kF_place<<<NBUCK, 256, 0, stream>>>(packedG, tot, sortedG, offsets, N, E);

    // 5) gather segment-sum -> z16
    k5_gather<<<3200, 256, 0, stream>>>(msg16, offsets, sortedG, z16, N);

    // 6) update MLP (MFMA) -> out
    k_mlp2<<<MB, 256, 0, stream>>>(z16, U1, c1, U2, c2, (float*)d_out, N);
}